// Round 12
// baseline (268.951 us; speedup 1.0000x reference)
//
#include <hip/hip_runtime.h>

#define B_   4
#define H_   8
#define M_   2048
#define D_   512
#define DH_  64

typedef short  bf16x8 __attribute__((ext_vector_type(8)));
typedef short  bf16x4 __attribute__((ext_vector_type(4)));
typedef float  f32x4  __attribute__((ext_vector_type(4)));
typedef unsigned short u16x4 __attribute__((ext_vector_type(4)));
typedef unsigned int   u32x2 __attribute__((ext_vector_type(2)));

#define EXPC 0.18033688011112042f   /* log2(e)/8 : exp(s/8) == exp2(s*EXPC) */

static __device__ __forceinline__ unsigned short f2bf(float f) {
  unsigned u = __float_as_uint(f);
  u += 0x7fffu + ((u >> 16) & 1u);
  return (unsigned short)(u >> 16);
}

// one instruction: [bf16(lo), bf16(hi)] packed into a u32 (RNE)
static __device__ __forceinline__ unsigned cvtpk(float lo, float hi) {
  unsigned r;
  asm("v_cvt_pk_bf16_f32 %0, %1, %2" : "=v"(r) : "v"(lo), "v"(hi));
  return r;
}

// PV matrix op: D = A(4 bf16, d-rows) x B(4 bf16, n-k) + C. ISA cdna4 §10.
static __device__ __forceinline__ f32x4 mfma16(bf16x4 a, bf16x4 b, f32x4 c) {
  asm("v_mfma_f32_16x16x16_bf16 %0, %1, %2, %0" : "+v"(c) : "v"(a), "v"(b));
  return c;
}

static __device__ __forceinline__ int swz128(int row, int byteoff) {
  return row * 128 + (byteoff ^ ((row & 7) << 4));
}

// async global->LDS, 16B per lane, LDS dest = wave-uniform base + lane*16
static __device__ __forceinline__ void glds16(const void* g, void* l) {
  __builtin_amdgcn_global_load_lds(
      (const __attribute__((address_space(1))) unsigned*)g,
      (__attribute__((address_space(3))) unsigned*)l, 16, 0, 0);
}

// stage a 128-row x 128-byte tile (16KB) into LDS in swz128 layout
static __device__ __forceinline__ void stage_tile(
    const char* g0, size_t rstride, char* lds, int t) {
  const int r0 = t >> 3, c0 = t & 7;
  const char* src = g0 + (size_t)r0 * rstride + ((c0 ^ (r0 & 7)) << 4);
  char* dst = lds + ((t & 192) << 4);
  #pragma unroll
  for (int c = 0; c < 4; ++c)
    glds16(src + (size_t)c * 32 * rstride, dst + c * 4096);
}

// stage a 64-row x 128-byte tile (8KB) into LDS in swz128 layout
static __device__ __forceinline__ void stage64(
    const char* g0, size_t rstride, char* lds, int t) {
  #pragma unroll
  for (int c = 0; c < 2; ++c) {
    int s = c * 256 + t;
    int row = s >> 3, ch = s & 7;
    const char* src = g0 + (size_t)row * rstride + ((ch ^ (row & 7)) << 4);
    glds16(src, lds + c * 4096 + ((t & 192) << 4));
  }
}

// ---------------- LayerNorm -> bf16 (vectorized: float4 in, u16x4 out) ------
// grid 4096, block 256: 2 rows per block, 128 threads (2 waves) per row.
__global__ __launch_bounds__(256) void ln_kernel(
    const float* __restrict__ x, const float* __restrict__ gamma,
    const float* __restrict__ beta, unsigned short* __restrict__ xn)
{
  const int t = threadIdx.x;
  const int half = t >> 7;                 // which of the 2 rows
  const int i = t & 127;                   // float4 index within row
  const int row = blockIdx.x * 2 + half;

  f32x4 v = *(const f32x4*)(x + (size_t)row * D_ + i * 4);
  float s  = v[0] + v[1] + v[2] + v[3];
  float ss = v[0]*v[0] + v[1]*v[1] + v[2]*v[2] + v[3]*v[3];
  #pragma unroll
  for (int m = 1; m < 64; m <<= 1) {
    s  += __shfl_xor(s, m);
    ss += __shfl_xor(ss, m);
  }
  __shared__ float red[2][2][2];
  const int w = (i >> 6) & 1;
  if ((i & 63) == 0) { red[half][w][0] = s; red[half][w][1] = ss; }
  __syncthreads();
  s  = red[half][0][0] + red[half][1][0];
  ss = red[half][0][1] + red[half][1][1];
  float mu  = s * (1.0f / D_);
  float var = ss * (1.0f / D_) - mu * mu;
  float rstd = rsqrtf(var + 1e-5f);

  f32x4 g4 = *(const f32x4*)(gamma + i * 4);
  f32x4 b4 = *(const f32x4*)(beta  + i * 4);
  u32x2 u;
  u[0] = cvtpk((v[0] - mu) * rstd * g4[0] + b4[0],
               (v[1] - mu) * rstd * g4[1] + b4[1]);
  u[1] = cvtpk((v[2] - mu) * rstd * g4[2] + b4[2],
               (v[3] - mu) * rstd * g4[3] + b4[3]);
  *(u32x2*)(xn + (size_t)row * D_ + i * 4) = u;
}

// ---------------- weight casts ----------------
__global__ __launch_bounds__(256) void cast_w_kernel(
    const float* __restrict__ wq, const float* __restrict__ wk,
    const float* __restrict__ wv, const float* __restrict__ wo,
    unsigned short* __restrict__ wqkv, unsigned short* __restrict__ wob)
{
  int i = blockIdx.x * 256 + threadIdx.x;   // 262144 total
  wqkv[i]          = f2bf(wq[i]);
  wqkv[i + 262144] = f2bf(wk[i]);
  wqkv[i + 524288] = f2bf(wv[i]);
  wob[i]           = f2bf(wo[i]);
}

// ---------------- QKV GEMM: q row-major, K/V in MFMA-fragment-packed layout -
__global__ __launch_bounds__(256) void qkv_gemm(
    const unsigned short* __restrict__ xn,
    const unsigned short* __restrict__ wqkv,
    const float* __restrict__ bq, const float* __restrict__ bk,
    const float* __restrict__ bv,
    unsigned short* __restrict__ q, unsigned short* __restrict__ Kp,
    unsigned short* __restrict__ Vp)
{
  __shared__ __align__(16) char As[128 * 128];
  __shared__ __align__(16) char Bs[128 * 128];
  const int m0 = blockIdx.x * 128;
  const int n0 = blockIdx.y * 128;
  const int t = threadIdx.x, wid = t >> 6, lane = t & 63;
  const int wr = (wid >> 1) * 64, wc = (wid & 1) * 64;
  const int cl = lane & 15, rg = lane >> 4;
  const f32x4 z4 = {0.f, 0.f, 0.f, 0.f};
  const bool isv = (n0 >= 1024);

  const char* agb = (const char*)xn   + (size_t)m0 * 1024;
  const char* bgb = (const char*)wqkv + (size_t)n0 * 1024;

  f32x4 acc[4][4];
  #pragma unroll
  for (int i = 0; i < 4; ++i)
    #pragma unroll
    for (int j = 0; j < 4; ++j) acc[i][j] = z4;

  for (int k0 = 0; k0 < 512; k0 += 64) {
    __syncthreads();
    stage_tile(agb + k0 * 2, 1024, As, t);
    stage_tile(bgb + k0 * 2, 1024, Bs, t);
    __syncthreads();
    #pragma unroll
    for (int ks = 0; ks < 2; ++ks) {
      int koff = ks * 64 + rg * 16;
      bf16x8 af[4], bfr[4];
      #pragma unroll
      for (int i = 0; i < 4; ++i)
        af[i] = *(const bf16x8*)(As + swz128(wr + i * 16 + cl, koff));
      #pragma unroll
      for (int j = 0; j < 4; ++j)
        bfr[j] = *(const bf16x8*)(Bs + swz128(wc + j * 16 + cl, koff));
      if (isv) {
        #pragma unroll
        for (int i = 0; i < 4; ++i)
          #pragma unroll
          for (int j = 0; j < 4; ++j)
            acc[i][j] = __builtin_amdgcn_mfma_f32_16x16x32_bf16(af[i], bfr[j], acc[i][j], 0, 0, 0);
      } else {
        #pragma unroll
        for (int j = 0; j < 4; ++j)
          #pragma unroll
          for (int i = 0; i < 4; ++i)
            acc[j][i] = __builtin_amdgcn_mfma_f32_16x16x32_bf16(bfr[j], af[i], acc[j][i], 0, 0, 0);
      }
    }
  }

  if (isv) {
    #pragma unroll
    for (int j = 0; j < 4; ++j) {
      int n = n0 + wc + j * 16 + cl;
      int nn = n & 511;
      int h = nn >> 6, dh = nn & 63;
      int jd = dh >> 4, cld = dh & 15;
      float bias = bv[nn];
      #pragma unroll
      for (int i = 0; i < 4; ++i) {
        int mrow = m0 + wr + i * 16 + rg * 4;
        int b = mrow >> 11, mm = mrow & 2047;
        int nt = mm >> 6, nl = mm & 63;
        int jp = nl >> 5, half = (nl >> 4) & 1, rgv = (nl >> 2) & 3;
        u32x2 u;
        u[0] = cvtpk(acc[i][j][0] + bias, acc[i][j][1] + bias);
        u[1] = cvtpk(acc[i][j][2] + bias, acc[i][j][3] + bias);
        size_t off = ((((size_t)(b * H_ + h) * 32 + nt) * 4 + jd) * 2 + jp) * 512
                   + (rgv * 16 + cld) * 8 + half * 4;
        *(u16x4*)(Vp + off) = __builtin_bit_cast(u16x4, u);
      }
    }
  } else {
    const int mat = n0 >> 9;                  // 0: q, 1: k
    #pragma unroll
    for (int j = 0; j < 4; ++j) {
      int nn0 = ((n0 + wc) & 511) + j * 16 + rg * 4;
      int h = nn0 >> 6, dh = nn0 & 63;
      f32x4 b4 = *(const f32x4*)((mat ? bk : bq) + nn0);
      #pragma unroll
      for (int i = 0; i < 4; ++i) {
        int mrow = m0 + wr + i * 16 + cl;
        int b = mrow >> 11, mm = mrow & 2047;
        u32x2 u;
        u[0] = cvtpk(acc[j][i][0] + b4[0], acc[j][i][1] + b4[1]);
        u[1] = cvtpk(acc[j][i][2] + b4[2], acc[j][i][3] + b4[3]);
        if (mat == 0) {
          *(u16x4*)(q + ((size_t)(b * H_ + h) * M_ + mm) * DH_ + dh) =
              __builtin_bit_cast(u16x4, u);
        } else {
          int ks = dh >> 5, rgk = (dh >> 3) & 3, e0 = dh & 7;   // e0 in {0,4}
          size_t off = ((((size_t)(b * H_ + h) * 32 + (mm >> 6)) * 4 + ((mm >> 4) & 3)) * 2 + ks) * 512
                     + (rgk * 16 + (mm & 15)) * 8 + e0;
          *(u16x4*)(Kp + off) = __builtin_bit_cast(u16x4, u);
        }
      }
    }
  }
}

// ---------------- Attention v12: zero-LDS, direct stores, fused normalize ---
// grid 1024 (XCD-swizzled); 64 rows/block, 4 waves x 16 rows. No LDS at all.
__global__ __launch_bounds__(256, 4) void attn_kernel(
    const unsigned short* __restrict__ q,
    const unsigned short* __restrict__ Kp,
    const unsigned short* __restrict__ Vp,
    float* __restrict__ attn,
    unsigned short* __restrict__ ctx)
{
  const int flat = blockIdx.x;
  const int bh = (flat & 7) * 4 + ((flat >> 3) >> 5);
  const int mb = (flat >> 3) & 31;
  const int m0 = mb * 64;
  const int t = threadIdx.x, wid = t >> 6, lane = t & 63;
  const int wr = wid * 16, cl = lane & 15, rg = lane >> 4;
  const int m_g = m0 + wr + cl;
  const f32x4 z4 = {0.f, 0.f, 0.f, 0.f};

  const char* qb = (const char*)(q + (size_t)bh * M_ * DH_);
  const unsigned short* kpb = Kp + (size_t)bh * 131072;   // 256 KB per bh
  const unsigned short* vpb = Vp + (size_t)bh * 131072;
  float* ab = attn + (size_t)bh * M_ * M_;

  bf16x8 qf[2];
  #pragma unroll
  for (int ks = 0; ks < 2; ++ks)
    qf[ks] = *(const bf16x8*)(qb + (size_t)m_g * 128 + ks * 64 + rg * 16);

  // ---- pass 1: psum (K fragments straight from packed L2) ----
  float psum = 0.f;
  for (int nt = 0; nt < 32; ++nt) {
    const unsigned short* kch = kpb + (size_t)nt * 4096;
    f32x4 s[4];
    #pragma unroll
    for (int j = 0; j < 4; ++j) s[j] = z4;
    #pragma unroll
    for (int ks = 0; ks < 2; ++ks)
      #pragma unroll
      for (int j = 0; j < 4; ++j) {
        bf16x8 kf = *(const bf16x8*)(kch + (j * 2 + ks) * 512 + lane * 8);
        s[j] = __builtin_amdgcn_mfma_f32_16x16x32_bf16(kf, qf[ks], s[j], 0, 0, 0);
      }
    if (nt == mb) {
      #pragma unroll
      for (int j = 0; j < 4; ++j)
        #pragma unroll
        for (int r = 0; r < 4; ++r) {
          int n_g = nt * 64 + j * 16 + rg * 4 + r;
          float p = __builtin_amdgcn_exp2f(s[j][r] * EXPC);
          psum += (n_g == m_g) ? 0.f : p;
        }
    } else {
      #pragma unroll
      for (int j = 0; j < 4; ++j)
        #pragma unroll
        for (int r = 0; r < 4; ++r)
          psum += __builtin_amdgcn_exp2f(s[j][r] * EXPC);
    }
  }
  psum += __shfl_xor(psum, 16);
  psum += __shfl_xor(psum, 32);
  const float lrv = -__log2f(psum);   // fold 1/psum into the exponent

  // ---- pass 2: recompute S, direct NT stores, PV in registers ----
  f32x4 oc[4];
  #pragma unroll
  for (int j = 0; j < 4; ++j) oc[j] = z4;

  asm volatile("s_nop 7" :::);         // VALU init -> asm MFMA srcC guard

  for (int nt = 0; nt < 32; ++nt) {
    const unsigned short* kch = kpb + (size_t)nt * 4096;
    const unsigned short* vch = vpb + (size_t)nt * 4096;
    f32x4 s[4];
    #pragma unroll
    for (int j = 0; j < 4; ++j) s[j] = z4;
    #pragma unroll
    for (int ks = 0; ks < 2; ++ks)
      #pragma unroll
      for (int j = 0; j < 4; ++j) {
        bf16x8 kf = *(const bf16x8*)(kch + (j * 2 + ks) * 512 + lane * 8);
        s[j] = __builtin_amdgcn_mfma_f32_16x16x32_bf16(kf, qf[ks], s[j], 0, 0, 0);
      }
    // P: p = exp2(s*EXPC + lrv), diag-masked. Lane owns row m_g,
    // cols nt*64 + j*16 + rg*4 + {0..3}: 16B contiguous -> direct NT store.
    // Within one store instr, lanes {cl, cl+16, cl+32, cl+48} cover 64B/row.
    const bool dtile = (nt == mb);
    bf16x4 pb[4];
    float* arow = ab + (size_t)m_g * M_ + nt * 64 + rg * 4;
    #pragma unroll
    for (int j = 0; j < 4; ++j) {
      f32x4 pv;
      #pragma unroll
      for (int r = 0; r < 4; ++r) {
        int n_g = nt * 64 + j * 16 + rg * 4 + r;
        float p = __builtin_amdgcn_exp2f(__builtin_fmaf(s[j][r], EXPC, lrv));
        pv[r] = (dtile && n_g == m_g) ? 0.f : p;
      }
      __builtin_nontemporal_store(pv, (f32x4*)(arow + j * 16));
      u32x2 uu;
      uu[0] = cvtpk(pv[0], pv[1]);
      uu[1] = cvtpk(pv[2], pv[3]);
      pb[j] = __builtin_bit_cast(bf16x4, uu);
    }
    // PV: oc[jd](d rows, m cols) += Vt-frag x P-frag, K=16 per j
    #pragma unroll
    for (int jp = 0; jp < 2; ++jp)
      #pragma unroll
      for (int jd = 0; jd < 4; ++jd) {
        bf16x8 w = *(const bf16x8*)(vch + (jd * 2 + jp) * 512 + lane * 8);
        bf16x4 vlo = __builtin_shufflevector(w, w, 0, 1, 2, 3);
        bf16x4 vhi = __builtin_shufflevector(w, w, 4, 5, 6, 7);
        oc[jd] = mfma16(vlo, pb[jp * 2],     oc[jd]);
        oc[jd] = mfma16(vhi, pb[jp * 2 + 1], oc[jd]);
      }
  }

  asm volatile("s_nop 7\n\ts_nop 7" :::);   // asm MFMA -> VALU read guard

  // ctx epilogue: lane holds 4 consecutive d for its row m_g
  int b = bh >> 3, h = bh & 7;
  unsigned short* crow = ctx + ((size_t)b * M_ + m_g) * D_ + h * DH_ + rg * 4;
  #pragma unroll
  for (int jd = 0; jd < 4; ++jd) {
    u32x2 u;
    u[0] = cvtpk(oc[jd][0], oc[jd][1]);
    u[1] = cvtpk(oc[jd][2], oc[jd][3]);
    *(u32x2*)(crow + jd * 16) = u;
  }
}

// ---------------- out = ctx @ wo^T + bo + x (128x64 tiles, 2 blocks/CU) -----
__global__ __launch_bounds__(256) void out_gemm(
    const unsigned short* __restrict__ ctxb,
    const unsigned short* __restrict__ wob,
    const float* __restrict__ bo,
    const float* __restrict__ x,
    float* __restrict__ out)
{
  __shared__ __align__(16) char As[128 * 128];
  __shared__ __align__(16) char Bs[64 * 128];
  const int m0 = blockIdx.x * 128;
  const int n0 = blockIdx.y * 64;
  const int t = threadIdx.x, wid = t >> 6, lane = t & 63;
  const int wr = (wid >> 1) * 64, wc = (wid & 1) * 32;
  const int cl = lane & 15, rg = lane >> 4;
  const f32x4 z4 = {0.f, 0.f, 0.f, 0.f};

  const char* agb = (const char*)ctxb + (size_t)m0 * 1024;
  const char* bgb = (const char*)wob  + (size_t)n0 * 1024;

  f32x4 acc[2][4];   // [j: n frag][i: m frag], row=n, col=m
  #pragma unroll
  for (int j = 0; j < 2; ++j)
    #pragma unroll
    for (int i = 0; i < 4; ++i) acc[j][i] = z4;

  for (int k0 = 0; k0 < 512; k0 += 64) {
    __syncthreads();
    stage_tile(agb + k0 * 2, 1024, As, t);
    stage64(bgb + k0 * 2, 1024, Bs, t);
    __syncthreads();
    #pragma unroll
    for (int ks = 0; ks < 2; ++ks) {
      int koff = ks * 64 + rg * 16;
      bf16x8 af[4], bfr[2];
      #pragma unroll
      for (int i = 0; i < 4; ++i)
        af[i] = *(const bf16x8*)(As + swz128(wr + i * 16 + cl, koff));
      #pragma unroll
      for (int j = 0; j < 2; ++j)
        bfr[j] = *(const bf16x8*)(Bs + swz128(wc + j * 16 + cl, koff));
      #pragma unroll
      for (int j = 0; j < 2; ++j)
        #pragma unroll
        for (int i = 0; i < 4; ++i)
          acc[j][i] = __builtin_amdgcn_mfma_f32_16x16x32_bf16(bfr[j], af[i], acc[j][i], 0, 0, 0);
    }
  }

  #pragma unroll
  for (int j = 0; j < 2; ++j) {
    int nb = n0 + wc + j * 16 + rg * 4;
    f32x4 bo4 = *(const f32x4*)(bo + nb);
    #pragma unroll
    for (int i = 0; i < 4; ++i) {
      int m = m0 + wr + i * 16 + cl;
      f32x4 x4 = *(const f32x4*)(x + (size_t)m * 512 + nb);
      f32x4 o;
      #pragma unroll
      for (int r = 0; r < 4; ++r) o[r] = acc[j][i][r] + bo4[r] + x4[r];
      *(f32x4*)(out + (size_t)m * 512 + nb) = o;
    }
  }
}

extern "C" void kernel_launch(void* const* d_in, const int* in_sizes, int n_in,
                              void* d_out, int out_size, void* d_ws, size_t ws_size,
                              hipStream_t stream) {
  const float* x     = (const float*)d_in[0];
  const float* wq    = (const float*)d_in[1];
  const float* bq    = (const float*)d_in[2];
  const float* wk    = (const float*)d_in[3];
  const float* bk    = (const float*)d_in[4];
  const float* wv    = (const float*)d_in[5];
  const float* bv    = (const float*)d_in[6];
  const float* wo    = (const float*)d_in[7];
  const float* bo    = (const float*)d_in[8];
  const float* gamma = (const float*)d_in[9];
  const float* beta  = (const float*)d_in[10];

  char* ws = (char*)d_ws;
  unsigned short* xn   = (unsigned short*)(ws);              //  8,388,608 B
  unsigned short* wqkv = (unsigned short*)(ws + 8388608);    //  1,572,864 B
  unsigned short* wob  = (unsigned short*)(ws + 9961472);    //    524,288 B
  unsigned short* qb   = (unsigned short*)(ws + 10485760);   //  8,388,608 B
  unsigned short* Kp   = (unsigned short*)(ws + 18874368);   //  8,388,608 B (packed)
  unsigned short* Vp   = (unsigned short*)(ws + 27262976);   //  8,388,608 B (packed)
  unsigned short* ctx  = (unsigned short*)(ws + 35651584);   //  8,388,608 B

  float* out  = (float*)d_out;
  float* attn = (float*)d_out + 4194304;

  ln_kernel<<<4096, 256, 0, stream>>>(x, gamma, beta, xn);
  cast_w_kernel<<<1024, 256, 0, stream>>>(wq, wk, wv, wo, wqkv, wob);
  qkv_gemm<<<dim3(64, 12), 256, 0, stream>>>(xn, wqkv, bq, bk, bv, qb, Kp, Vp);
  attn_kernel<<<1024, 256, 0, stream>>>(qb, Kp, Vp, attn, ctx);
  out_gemm<<<dim3(64, 8), 256, 0, stream>>>(ctx, wob, bo, x, out);
}

// Round 13
// 198.343 us; speedup vs baseline: 1.3560x; 1.3560x over previous
//
#include <hip/hip_runtime.h>

#define B_   4
#define H_   8
#define M_   2048
#define D_   512
#define DH_  64

typedef short  bf16x8 __attribute__((ext_vector_type(8)));
typedef short  bf16x4 __attribute__((ext_vector_type(4)));
typedef float  f32x4  __attribute__((ext_vector_type(4)));
typedef unsigned short u16x4 __attribute__((ext_vector_type(4)));
typedef unsigned int   u32x2 __attribute__((ext_vector_type(2)));

#define EXPC 0.18033688011112042f   /* log2(e)/8 : exp(s/8) == exp2(s*EXPC) */

static __device__ __forceinline__ unsigned short f2bf(float f) {
  unsigned u = __float_as_uint(f);
  u += 0x7fffu + ((u >> 16) & 1u);
  return (unsigned short)(u >> 16);
}

// one instruction: [bf16(lo), bf16(hi)] packed into a u32 (RNE)
static __device__ __forceinline__ unsigned cvtpk(float lo, float hi) {
  unsigned r;
  asm("v_cvt_pk_bf16_f32 %0, %1, %2" : "=v"(r) : "v"(lo), "v"(hi));
  return r;
}

// PV matrix op: D = A(4 bf16, d-rows) x B(4 bf16, n-k) + C. ISA cdna4 §10.
static __device__ __forceinline__ f32x4 mfma16(bf16x4 a, bf16x4 b, f32x4 c) {
  asm("v_mfma_f32_16x16x16_bf16 %0, %1, %2, %0" : "+v"(c) : "v"(a), "v"(b));
  return c;
}

static __device__ __forceinline__ int swz128(int row, int byteoff) {
  return row * 128 + (byteoff ^ ((row & 7) << 4));
}

// async global->LDS, 16B per lane, LDS dest = wave-uniform base + lane*16
static __device__ __forceinline__ void glds16(const void* g, void* l) {
  __builtin_amdgcn_global_load_lds(
      (const __attribute__((address_space(1))) unsigned*)g,
      (__attribute__((address_space(3))) unsigned*)l, 16, 0, 0);
}

// stage a 128-row x 128-byte tile (16KB) into LDS in swz128 layout
static __device__ __forceinline__ void stage_tile(
    const char* g0, size_t rstride, char* lds, int t) {
  const int r0 = t >> 3, c0 = t & 7;
  const char* src = g0 + (size_t)r0 * rstride + ((c0 ^ (r0 & 7)) << 4);
  char* dst = lds + ((t & 192) << 4);
  #pragma unroll
  for (int c = 0; c < 4; ++c)
    glds16(src + (size_t)c * 32 * rstride, dst + c * 4096);
}

// stage a 64-row x 128-byte tile (8KB) into LDS in swz128 layout
static __device__ __forceinline__ void stage64(
    const char* g0, size_t rstride, char* lds, int t) {
  #pragma unroll
  for (int c = 0; c < 2; ++c) {
    int s = c * 256 + t;
    int row = s >> 3, ch = s & 7;
    const char* src = g0 + (size_t)row * rstride + ((ch ^ (row & 7)) << 4);
    glds16(src, lds + c * 4096 + ((t & 192) << 4));
  }
}

// ---------------- LayerNorm -> bf16 (vectorized: float4 in, u16x4 out) ------
// grid 4096, block 256: 2 rows per block, 128 threads (2 waves) per row.
__global__ __launch_bounds__(256) void ln_kernel(
    const float* __restrict__ x, const float* __restrict__ gamma,
    const float* __restrict__ beta, unsigned short* __restrict__ xn)
{
  const int t = threadIdx.x;
  const int half = t >> 7;                 // which of the 2 rows
  const int i = t & 127;                   // float4 index within row
  const int row = blockIdx.x * 2 + half;

  f32x4 v = *(const f32x4*)(x + (size_t)row * D_ + i * 4);
  float s  = v[0] + v[1] + v[2] + v[3];
  float ss = v[0]*v[0] + v[1]*v[1] + v[2]*v[2] + v[3]*v[3];
  #pragma unroll
  for (int m = 1; m < 64; m <<= 1) {
    s  += __shfl_xor(s, m);
    ss += __shfl_xor(ss, m);
  }
  __shared__ float red[2][2][2];
  const int w = (i >> 6) & 1;
  if ((i & 63) == 0) { red[half][w][0] = s; red[half][w][1] = ss; }
  __syncthreads();
  s  = red[half][0][0] + red[half][1][0];
  ss = red[half][0][1] + red[half][1][1];
  float mu  = s * (1.0f / D_);
  float var = ss * (1.0f / D_) - mu * mu;
  float rstd = rsqrtf(var + 1e-5f);

  f32x4 g4 = *(const f32x4*)(gamma + i * 4);
  f32x4 b4 = *(const f32x4*)(beta  + i * 4);
  u32x2 u;
  u[0] = cvtpk((v[0] - mu) * rstd * g4[0] + b4[0],
               (v[1] - mu) * rstd * g4[1] + b4[1]);
  u[1] = cvtpk((v[2] - mu) * rstd * g4[2] + b4[2],
               (v[3] - mu) * rstd * g4[3] + b4[3]);
  *(u32x2*)(xn + (size_t)row * D_ + i * 4) = u;
}

// ---------------- weight casts ----------------
__global__ __launch_bounds__(256) void cast_w_kernel(
    const float* __restrict__ wq, const float* __restrict__ wk,
    const float* __restrict__ wv, const float* __restrict__ wo,
    unsigned short* __restrict__ wqkv, unsigned short* __restrict__ wob)
{
  int i = blockIdx.x * 256 + threadIdx.x;   // 262144 total
  wqkv[i]          = f2bf(wq[i]);
  wqkv[i + 262144] = f2bf(wk[i]);
  wqkv[i + 524288] = f2bf(wv[i]);
  wob[i]           = f2bf(wo[i]);
}

// ---------------- QKV GEMM: q row-major, K/V in MFMA-fragment-packed layout -
__global__ __launch_bounds__(256) void qkv_gemm(
    const unsigned short* __restrict__ xn,
    const unsigned short* __restrict__ wqkv,
    const float* __restrict__ bq, const float* __restrict__ bk,
    const float* __restrict__ bv,
    unsigned short* __restrict__ q, unsigned short* __restrict__ Kp,
    unsigned short* __restrict__ Vp)
{
  __shared__ __align__(16) char As[128 * 128];
  __shared__ __align__(16) char Bs[128 * 128];
  const int m0 = blockIdx.x * 128;
  const int n0 = blockIdx.y * 128;
  const int t = threadIdx.x, wid = t >> 6, lane = t & 63;
  const int wr = (wid >> 1) * 64, wc = (wid & 1) * 64;
  const int cl = lane & 15, rg = lane >> 4;
  const f32x4 z4 = {0.f, 0.f, 0.f, 0.f};
  const bool isv = (n0 >= 1024);

  const char* agb = (const char*)xn   + (size_t)m0 * 1024;
  const char* bgb = (const char*)wqkv + (size_t)n0 * 1024;

  f32x4 acc[4][4];
  #pragma unroll
  for (int i = 0; i < 4; ++i)
    #pragma unroll
    for (int j = 0; j < 4; ++j) acc[i][j] = z4;

  for (int k0 = 0; k0 < 512; k0 += 64) {
    __syncthreads();
    stage_tile(agb + k0 * 2, 1024, As, t);
    stage_tile(bgb + k0 * 2, 1024, Bs, t);
    __syncthreads();
    #pragma unroll
    for (int ks = 0; ks < 2; ++ks) {
      int koff = ks * 64 + rg * 16;
      bf16x8 af[4], bfr[4];
      #pragma unroll
      for (int i = 0; i < 4; ++i)
        af[i] = *(const bf16x8*)(As + swz128(wr + i * 16 + cl, koff));
      #pragma unroll
      for (int j = 0; j < 4; ++j)
        bfr[j] = *(const bf16x8*)(Bs + swz128(wc + j * 16 + cl, koff));
      if (isv) {
        #pragma unroll
        for (int i = 0; i < 4; ++i)
          #pragma unroll
          for (int j = 0; j < 4; ++j)
            acc[i][j] = __builtin_amdgcn_mfma_f32_16x16x32_bf16(af[i], bfr[j], acc[i][j], 0, 0, 0);
      } else {
        #pragma unroll
        for (int j = 0; j < 4; ++j)
          #pragma unroll
          for (int i = 0; i < 4; ++i)
            acc[j][i] = __builtin_amdgcn_mfma_f32_16x16x32_bf16(bfr[j], af[i], acc[j][i], 0, 0, 0);
      }
    }
  }

  if (isv) {
    #pragma unroll
    for (int j = 0; j < 4; ++j) {
      int n = n0 + wc + j * 16 + cl;
      int nn = n & 511;
      int h = nn >> 6, dh = nn & 63;
      int jd = dh >> 4, cld = dh & 15;
      float bias = bv[nn];
      #pragma unroll
      for (int i = 0; i < 4; ++i) {
        int mrow = m0 + wr + i * 16 + rg * 4;
        int b = mrow >> 11, mm = mrow & 2047;
        int nt = mm >> 6, nl = mm & 63;
        int jp = nl >> 5, half = (nl >> 4) & 1, rgv = (nl >> 2) & 3;
        u32x2 u;
        u[0] = cvtpk(acc[i][j][0] + bias, acc[i][j][1] + bias);
        u[1] = cvtpk(acc[i][j][2] + bias, acc[i][j][3] + bias);
        size_t off = ((((size_t)(b * H_ + h) * 32 + nt) * 4 + jd) * 2 + jp) * 512
                   + (rgv * 16 + cld) * 8 + half * 4;
        *(u16x4*)(Vp + off) = __builtin_bit_cast(u16x4, u);
      }
    }
  } else {
    const int mat = n0 >> 9;                  // 0: q, 1: k
    #pragma unroll
    for (int j = 0; j < 4; ++j) {
      int nn0 = ((n0 + wc) & 511) + j * 16 + rg * 4;
      int h = nn0 >> 6, dh = nn0 & 63;
      f32x4 b4 = *(const f32x4*)((mat ? bk : bq) + nn0);
      #pragma unroll
      for (int i = 0; i < 4; ++i) {
        int mrow = m0 + wr + i * 16 + cl;
        int b = mrow >> 11, mm = mrow & 2047;
        u32x2 u;
        u[0] = cvtpk(acc[j][i][0] + b4[0], acc[j][i][1] + b4[1]);
        u[1] = cvtpk(acc[j][i][2] + b4[2], acc[j][i][3] + b4[3]);
        if (mat == 0) {
          *(u16x4*)(q + ((size_t)(b * H_ + h) * M_ + mm) * DH_ + dh) =
              __builtin_bit_cast(u16x4, u);
        } else {
          int ks = dh >> 5, rgk = (dh >> 3) & 3, e0 = dh & 7;   // e0 in {0,4}
          size_t off = ((((size_t)(b * H_ + h) * 32 + (mm >> 6)) * 4 + ((mm >> 4) & 3)) * 2 + ks) * 512
                     + (rgk * 16 + (mm & 15)) * 8 + e0;
          *(u16x4*)(Kp + off) = __builtin_bit_cast(u16x4, u);
        }
      }
    }
  }
}

// ---------------- Attention (R8 v8): fused, zero-barrier, packed K/V --------
// grid 1024 (XCD-swizzled); 64 rows/block, 4 waves x 16 rows. LDS 8KB (Ps).
__global__ __launch_bounds__(256, 4) void attn_kernel(
    const unsigned short* __restrict__ q,
    const unsigned short* __restrict__ Kp,
    const unsigned short* __restrict__ Vp,
    float* __restrict__ attn,
    unsigned short* __restrict__ ctx)
{
  __shared__ __align__(16) char Ps[4][2048];

  const int flat = blockIdx.x;
  const int bh = (flat & 7) * 4 + ((flat >> 3) >> 5);
  const int mb = (flat >> 3) & 31;
  const int m0 = mb * 64;
  const int t = threadIdx.x, wid = t >> 6, lane = t & 63;
  const int wr = wid * 16, cl = lane & 15, rg = lane >> 4;
  const int m_g = m0 + wr + cl;
  const f32x4 z4 = {0.f, 0.f, 0.f, 0.f};

  const char* qb = (const char*)(q + (size_t)bh * M_ * DH_);
  const unsigned short* kpb = Kp + (size_t)bh * 131072;   // 256 KB per bh
  const unsigned short* vpb = Vp + (size_t)bh * 131072;
  float* ab = attn + (size_t)bh * M_ * M_;

  bf16x8 qf[2];
  #pragma unroll
  for (int ks = 0; ks < 2; ++ks)
    qf[ks] = *(const bf16x8*)(qb + (size_t)m_g * 128 + ks * 64 + rg * 16);

  // ---- pass 1: psum (no barriers, K fragments straight from packed L2) ----
  float psum = 0.f;
  for (int nt = 0; nt < 32; ++nt) {
    const unsigned short* kch = kpb + (size_t)nt * 4096;
    f32x4 s[4];
    #pragma unroll
    for (int j = 0; j < 4; ++j) s[j] = z4;
    #pragma unroll
    for (int ks = 0; ks < 2; ++ks)
      #pragma unroll
      for (int j = 0; j < 4; ++j) {
        bf16x8 kf = *(const bf16x8*)(kch + (j * 2 + ks) * 512 + lane * 8);
        s[j] = __builtin_amdgcn_mfma_f32_16x16x32_bf16(kf, qf[ks], s[j], 0, 0, 0);
      }
    if (nt == mb) {
      #pragma unroll
      for (int j = 0; j < 4; ++j)
        #pragma unroll
        for (int r = 0; r < 4; ++r) {
          int n_g = nt * 64 + j * 16 + rg * 4 + r;
          float p = __builtin_amdgcn_exp2f(s[j][r] * EXPC);
          psum += (n_g == m_g) ? 0.f : p;
        }
    } else {
      #pragma unroll
      for (int j = 0; j < 4; ++j)
        #pragma unroll
        for (int r = 0; r < 4; ++r)
          psum += __builtin_amdgcn_exp2f(s[j][r] * EXPC);
    }
  }
  psum += __shfl_xor(psum, 16);
  psum += __shfl_xor(psum, 32);
  const float rv = 1.0f / psum;

  // ---- pass 2: recompute S, attn store, PV via direct register feed ----
  f32x4 oc[4];
  #pragma unroll
  for (int j = 0; j < 4; ++j) oc[j] = z4;

  const int srow = lane >> 4;          // attn-store row-in-group 0..3
  const int sch  = lane & 15;          // attn-store 16B-chunk 0..15

  asm volatile("s_nop 7" :::);         // VALU init -> asm MFMA srcC guard

  for (int nt = 0; nt < 32; ++nt) {
    const unsigned short* kch = kpb + (size_t)nt * 4096;
    const unsigned short* vch = vpb + (size_t)nt * 4096;
    f32x4 s[4];
    #pragma unroll
    for (int j = 0; j < 4; ++j) s[j] = z4;
    #pragma unroll
    for (int ks = 0; ks < 2; ++ks)
      #pragma unroll
      for (int j = 0; j < 4; ++j) {
        bf16x8 kf = *(const bf16x8*)(kch + (j * 2 + ks) * 512 + lane * 8);
        s[j] = __builtin_amdgcn_mfma_f32_16x16x32_bf16(kf, qf[ks], s[j], 0, 0, 0);
      }
    // P: normalized, diag-masked; bf16x4 per j feeds PV directly (B-operand
    // of 16x16x16: col=lane&15=m, k=(lane>>4)*4+0..3=n -- exact S layout).
    const bool dtile = (nt == mb);
    bf16x4 pb[4];
    #pragma unroll
    for (int j = 0; j < 4; ++j) {
      f32x4 pv;
      #pragma unroll
      for (int r = 0; r < 4; ++r) {
        int n_g = nt * 64 + j * 16 + rg * 4 + r;
        float p = __builtin_amdgcn_exp2f(s[j][r] * EXPC) * rv;
        pv[r] = (dtile && n_g == m_g) ? 0.f : p;
      }
      u32x2 uu;
      uu[0] = cvtpk(pv[0], pv[1]);
      uu[1] = cvtpk(pv[2], pv[3]);
      pb[j] = __builtin_bit_cast(bf16x4, uu);
      *(u32x2*)(Ps[wid] + swz128(cl, j * 32 + rg * 8)) = uu;  // per-wave: no barrier
    }
    // attn store: dense 4 rows x 256B per instruction group (NT, stays in flight)
    {
      float* abase = ab + ((size_t)(m0 + wr + srow)) * M_ + nt * 64 + sch * 4;
      #pragma unroll
      for (int it = 0; it < 4; ++it) {
        u16x4 pu = *(const u16x4*)(Ps[wid] + swz128(it * 4 + srow, sch * 8));
        f32x4 pv;
        #pragma unroll
        for (int r = 0; r < 4; ++r) pv[r] = __uint_as_float((unsigned)pu[r] << 16);
        __builtin_nontemporal_store(pv, (f32x4*)(abase + (size_t)it * 4 * M_));
      }
    }
    // PV: oc[jd](d rows, m cols) += Vt-frag x P-frag, K=16 per j
    #pragma unroll
    for (int jp = 0; jp < 2; ++jp)
      #pragma unroll
      for (int jd = 0; jd < 4; ++jd) {
        bf16x8 w = *(const bf16x8*)(vch + (jd * 2 + jp) * 512 + lane * 8);
        bf16x4 vlo = __builtin_shufflevector(w, w, 0, 1, 2, 3);
        bf16x4 vhi = __builtin_shufflevector(w, w, 4, 5, 6, 7);
        oc[jd] = mfma16(vlo, pb[jp * 2],     oc[jd]);
        oc[jd] = mfma16(vhi, pb[jp * 2 + 1], oc[jd]);
      }
  }

  asm volatile("s_nop 7\n\ts_nop 7" :::);   // asm MFMA -> VALU read guard

  // ctx epilogue: lane holds 4 consecutive d for its row m_g
  int b = bh >> 3, h = bh & 7;
  unsigned short* crow = ctx + ((size_t)b * M_ + m_g) * D_ + h * DH_ + rg * 4;
  #pragma unroll
  for (int jd = 0; jd < 4; ++jd) {
    u32x2 u;
    u[0] = cvtpk(oc[jd][0], oc[jd][1]);
    u[1] = cvtpk(oc[jd][2], oc[jd][3]);
    *(u32x2*)(crow + jd * 16) = u;
  }
}

// ---------------- out = ctx @ wo^T + bo + x (128x64 tiles, 2 blocks/CU) -----
__global__ __launch_bounds__(256) void out_gemm(
    const unsigned short* __restrict__ ctxb,
    const unsigned short* __restrict__ wob,
    const float* __restrict__ bo,
    const float* __restrict__ x,
    float* __restrict__ out)
{
  __shared__ __align__(16) char As[128 * 128];
  __shared__ __align__(16) char Bs[64 * 128];
  const int m0 = blockIdx.x * 128;
  const int n0 = blockIdx.y * 64;
  const int t = threadIdx.x, wid = t >> 6, lane = t & 63;
  const int wr = (wid >> 1) * 64, wc = (wid & 1) * 32;
  const int cl = lane & 15, rg = lane >> 4;
  const f32x4 z4 = {0.f, 0.f, 0.f, 0.f};

  const char* agb = (const char*)ctxb + (size_t)m0 * 1024;
  const char* bgb = (const char*)wob  + (size_t)n0 * 1024;

  f32x4 acc[2][4];   // [j: n frag][i: m frag], row=n, col=m
  #pragma unroll
  for (int j = 0; j < 2; ++j)
    #pragma unroll
    for (int i = 0; i < 4; ++i) acc[j][i] = z4;

  for (int k0 = 0; k0 < 512; k0 += 64) {
    __syncthreads();
    stage_tile(agb + k0 * 2, 1024, As, t);
    stage64(bgb + k0 * 2, 1024, Bs, t);
    __syncthreads();
    #pragma unroll
    for (int ks = 0; ks < 2; ++ks) {
      int koff = ks * 64 + rg * 16;
      bf16x8 af[4], bfr[2];
      #pragma unroll
      for (int i = 0; i < 4; ++i)
        af[i] = *(const bf16x8*)(As + swz128(wr + i * 16 + cl, koff));
      #pragma unroll
      for (int j = 0; j < 2; ++j)
        bfr[j] = *(const bf16x8*)(Bs + swz128(wc + j * 16 + cl, koff));
      #pragma unroll
      for (int j = 0; j < 2; ++j)
        #pragma unroll
        for (int i = 0; i < 4; ++i)
          acc[j][i] = __builtin_amdgcn_mfma_f32_16x16x32_bf16(bfr[j], af[i], acc[j][i], 0, 0, 0);
    }
  }

  #pragma unroll
  for (int j = 0; j < 2; ++j) {
    int nb = n0 + wc + j * 16 + rg * 4;
    f32x4 bo4 = *(const f32x4*)(bo + nb);
    #pragma unroll
    for (int i = 0; i < 4; ++i) {
      int m = m0 + wr + i * 16 + cl;
      f32x4 x4 = *(const f32x4*)(x + (size_t)m * 512 + nb);
      f32x4 o;
      #pragma unroll
      for (int r = 0; r < 4; ++r) o[r] = acc[j][i][r] + bo4[r] + x4[r];
      *(f32x4*)(out + (size_t)m * 512 + nb) = o;
    }
  }
}

extern "C" void kernel_launch(void* const* d_in, const int* in_sizes, int n_in,
                              void* d_out, int out_size, void* d_ws, size_t ws_size,
                              hipStream_t stream) {
  const float* x     = (const float*)d_in[0];
  const float* wq    = (const float*)d_in[1];
  const float* bq    = (const float*)d_in[2];
  const float* wk    = (const float*)d_in[3];
  const float* bk    = (const float*)d_in[4];
  const float* wv    = (const float*)d_in[5];
  const float* bv    = (const float*)d_in[6];
  const float* wo    = (const float*)d_in[7];
  const float* bo    = (const float*)d_in[8];
  const float* gamma = (const float*)d_in[9];
  const float* beta  = (const float*)d_in[10];

  char* ws = (char*)d_ws;
  unsigned short* xn   = (unsigned short*)(ws);              //  8,388,608 B
  unsigned short* wqkv = (unsigned short*)(ws + 8388608);    //  1,572,864 B
  unsigned short* wob  = (unsigned short*)(ws + 9961472);    //    524,288 B
  unsigned short* qb   = (unsigned short*)(ws + 10485760);   //  8,388,608 B
  unsigned short* Kp   = (unsigned short*)(ws + 18874368);   //  8,388,608 B (packed)
  unsigned short* Vp   = (unsigned short*)(ws + 27262976);   //  8,388,608 B (packed)
  unsigned short* ctx  = (unsigned short*)(ws + 35651584);   //  8,388,608 B

  float* out  = (float*)d_out;
  float* attn = (float*)d_out + 4194304;

  ln_kernel<<<4096, 256, 0, stream>>>(x, gamma, beta, xn);
  cast_w_kernel<<<1024, 256, 0, stream>>>(wq, wk, wv, wo, wqkv, wob);
  qkv_gemm<<<dim3(64, 12), 256, 0, stream>>>(xn, wqkv, bq, bk, bv, qb, Kp, Vp);
  attn_kernel<<<1024, 256, 0, stream>>>(qb, Kp, Vp, attn, ctx);
  out_gemm<<<dim3(64, 8), 256, 0, stream>>>(ctx, wob, bo, x, out);
}